// Round 4
// baseline (942.033 us; speedup 1.0000x reference)
//
#include <hip/hip_runtime.h>
#include <math.h>

#define NN 100000
#define NE 1600000
#define NG 1024
#define EPSB 1e-5f

typedef _Float16 h16;
typedef __attribute__((ext_vector_type(2))) _Float16 h16x2;
typedef __attribute__((ext_vector_type(8))) _Float16 h16x8;
typedef __attribute__((ext_vector_type(4))) float f32x4;

static __device__ __forceinline__ float sigmoidf_(float x){ return 1.f/(1.f+__expf(-x)); }

// ---------------- CSR build ----------------
__global__ void k_count(const int* __restrict__ src, const int* __restrict__ dst,
                        int* __restrict__ degO, int* __restrict__ cnt){
  int e = blockIdx.x*256 + threadIdx.x;
  if (e < NE){ atomicAdd(&degO[src[e]], 1); atomicAdd(&cnt[dst[e]], 1); }
}

__global__ void k_norms(const int* __restrict__ degO, const int* __restrict__ degI,
                        float* __restrict__ ns, float* __restrict__ nd){
  int v = blockIdx.x*256 + threadIdx.x;
  if (v < NN){
    ns[v] = rsqrtf(fmaxf((float)degO[v], 1.f));
    nd[v] = rsqrtf(fmaxf((float)degI[v], 1.f));
  }
  if (v == 0) ns[NN] = 0.f;   // dummy node kills padded-slot contributions
}

// exclusive scan of aligned-degree (ceil(deg/4)*4), 3-phase
__global__ void k_scan1(const int* __restrict__ cnt, int* __restrict__ off, int* __restrict__ bsum){
  __shared__ int s[256];
  int t = threadIdx.x, v = blockIdx.x*256 + t;
  int d = (v < NN) ? cnt[v] : 0;
  int ad = (d + 3) & ~3;
  s[t] = ad; __syncthreads();
  #pragma unroll
  for (int o=1;o<256;o<<=1){ int y=(t>=o)?s[t-o]:0; __syncthreads(); s[t]+=y; __syncthreads(); }
  int incl = s[t];
  if (v < NN) off[v] = incl - ad;
  if (t == 255) bsum[blockIdx.x] = incl;
}

__global__ void k_scan2(int* __restrict__ bsum, int* __restrict__ off, int nb){
  __shared__ int s[512];
  int t = threadIdx.x;
  int x = (t < nb) ? bsum[t] : 0;
  s[t] = x; __syncthreads();
  #pragma unroll
  for (int o=1;o<512;o<<=1){ int y=(t>=o)?s[t-o]:0; __syncthreads(); s[t]+=y; __syncthreads(); }
  int incl = s[t];
  if (t < nb) bsum[t] = incl - x;
  if (t == nb-1) off[NN] = incl;
}

__global__ void k_scan3(int* __restrict__ off, const int* __restrict__ bsum){
  int v = blockIdx.x*256 + threadIdx.x;
  if (v < NN) off[v] += bsum[blockIdx.x];
}

__global__ void k_fillcsr(const int* __restrict__ src, const int* __restrict__ dst,
                          const int* __restrict__ off, int* __restrict__ cnt2,
                          int* __restrict__ eidx){
  int e = blockIdx.x*256 + threadIdx.x;
  if (e < NE){
    int d = dst[e];
    int p = atomicAdd(&cnt2[d], 1);
    eidx[off[d] + p] = src[e];
  }
}

__global__ void k_pad(const int* __restrict__ cnt, const int* __restrict__ off,
                      int* __restrict__ eidx){
  int v = blockIdx.x*256 + threadIdx.x;
  if (v < NN){
    int d = cnt[v];
    int ad = (d + 3) & ~3;
    int base = off[v] + d;
    for (int i=0;i<ad-d;i++) eidx[base+i] = NN;
  }
}

// ---------------- weight convert: W fp32 [K][Nc] -> Wt fp16 [Nc][Kpad]
__global__ void k_convW(const float* __restrict__ W, h16* __restrict__ Wt,
                        int K, int Nc, int Kpad){
  int i = blockIdx.x*256 + threadIdx.x;
  if (i >= Nc*Kpad) return;
  int c = i / Kpad, k = i % Kpad;
  Wt[i] = (k < K) ? (h16)W[(size_t)k*Nc + c] : (h16)0.f;
}

// ---------------- layer-1 prep: hn fp16 [(NN+1)][40] = h*ns, dummy row 0
__global__ void k_prep1(const float* __restrict__ h, const float* __restrict__ ns,
                        h16* __restrict__ hn){
  int i = blockIdx.x*256 + threadIdx.x;
  if (i >= (NN+1)*40) return;
  int v = i / 40, c = i - v*40;
  float val = (v < NN && c < 38) ? h[(size_t)v*38 + c]*ns[v] : 0.f;
  hn[i] = (h16)val;
}

// ---------------- layer-1 gather: sum hn rows -> A38 fp16 [NN][64]
__global__ __launch_bounds__(256)
void k_gs40(const h16* __restrict__ hn, const int* __restrict__ eidx,
            const int* __restrict__ off, const float* __restrict__ nd,
            h16* __restrict__ A38){
  int v = (blockIdx.x*256 + threadIdx.x) >> 6;
  int lane = threadIdx.x & 63;
  if (v >= NN) return;
  int ab = off[v], ae = off[v+1];
  int c0 = 2*lane;
  float a0=0.f, a1=0.f;
  for (int e=ab; e<ae; e+=4){
    int4 s4 = *(const int4*)(eidx + e);
    if (lane < 20){
      h16x2 u0 = *(const h16x2*)(hn + (size_t)s4.x*40 + c0);
      h16x2 u1 = *(const h16x2*)(hn + (size_t)s4.y*40 + c0);
      h16x2 u2 = *(const h16x2*)(hn + (size_t)s4.z*40 + c0);
      h16x2 u3 = *(const h16x2*)(hn + (size_t)s4.w*40 + c0);
      a0 += (float)u0[0] + (float)u1[0] + (float)u2[0] + (float)u3[0];
      a1 += (float)u0[1] + (float)u1[1] + (float)u2[1] + (float)u3[1];
    }
  }
  if (lane < 32){
    float ndv = nd[v];
    h16x2 o; o[0] = (h16)0.f; o[1] = (h16)0.f;
    if (lane < 20){ o[0] = (h16)(a0*ndv); o[1] = (h16)(a1*ndv); }
    *(h16x2*)(A38 + (size_t)v*64 + c0) = o;
  }
}

// ---------------- layers 2..4 gather, BN+ReLU+ns fused, fp16 X rows ----------------
__global__ __launch_bounds__(256)
void k_gs128(const h16* __restrict__ X, const int* __restrict__ eidx,
             const int* __restrict__ off, const float* __restrict__ ns,
             const float* __restrict__ nd, const float* __restrict__ scale,
             const float* __restrict__ shift, h16* __restrict__ agg){
  int v = (blockIdx.x*256 + threadIdx.x) >> 6;
  int lane = threadIdx.x & 63;
  if (v >= NN) return;
  int ab = off[v], ae = off[v+1];
  int c0 = 2*lane;
  float sc0 = scale[c0], sc1 = scale[c0+1];
  float sh0 = shift[c0], sh1 = shift[c0+1];
  float a0=0.f, a1=0.f;
  for (int e=ab; e<ae; e+=4){
    int4 s4 = *(const int4*)(eidx + e);
    float w0 = ns[s4.x], w1 = ns[s4.y], w2 = ns[s4.z], w3 = ns[s4.w];
    h16x2 u0 = *(const h16x2*)(X + (size_t)s4.x*128 + c0);
    h16x2 u1 = *(const h16x2*)(X + (size_t)s4.y*128 + c0);
    h16x2 u2 = *(const h16x2*)(X + (size_t)s4.z*128 + c0);
    h16x2 u3 = *(const h16x2*)(X + (size_t)s4.w*128 + c0);
    a0 = fmaf(fmaxf(fmaf((float)u0[0], sc0, sh0), 0.f), w0, a0);
    a1 = fmaf(fmaxf(fmaf((float)u0[1], sc1, sh1), 0.f), w0, a1);
    a0 = fmaf(fmaxf(fmaf((float)u1[0], sc0, sh0), 0.f), w1, a0);
    a1 = fmaf(fmaxf(fmaf((float)u1[1], sc1, sh1), 0.f), w1, a1);
    a0 = fmaf(fmaxf(fmaf((float)u2[0], sc0, sh0), 0.f), w2, a0);
    a1 = fmaf(fmaxf(fmaf((float)u2[1], sc1, sh1), 0.f), w2, a1);
    a0 = fmaf(fmaxf(fmaf((float)u3[0], sc0, sh0), 0.f), w3, a0);
    a1 = fmaf(fmaxf(fmaf((float)u3[1], sc1, sh1), 0.f), w3, a1);
  }
  float ndv = nd[v];
  h16x2 o; o[0] = (h16)(a0*ndv); o[1] = (h16)(a1*ndv);
  *(h16x2*)(agg + (size_t)v*128 + c0) = o;
}

// ---------------- MFMA GEMM fp16 (tile 128x128, 4 waves, BK=64), fused BN stats ----------------
__global__ __launch_bounds__(256)
void k_mgemm(const h16* __restrict__ A, const h16* __restrict__ Wt,
             const float* __restrict__ bias, h16* __restrict__ Cout,
             float* __restrict__ stats, int M, int K, int Nc){
  __shared__ h16 As[128][72];
  __shared__ h16 Bs[128][72];
  __shared__ float sred[2][128];
  int m0 = blockIdx.x*128, n0 = blockIdx.y*128;
  int t = threadIdx.x, w = t>>6, lane = t&63;
  int wr = (w>>1)*64, wc = (w&1)*64;
  f32x4 acc[4][4] = {};

  int ar = t>>3;
  int ac = (t&7)*8;
  for (int k0=0; k0<K; k0+=64){
    #pragma unroll
    for (int rr=0; rr<128; rr+=32){
      int gm = m0 + ar + rr;
      h16x8 val = {};
      if (gm < M) val = *(const h16x8*)(A + (size_t)gm*K + k0 + ac);
      *(h16x8*)&As[ar+rr][ac] = val;
    }
    #pragma unroll
    for (int rr=0; rr<128; rr+=32){
      int gc = n0 + ar + rr;
      h16x8 val = {};
      if (gc < Nc) val = *(const h16x8*)(Wt + (size_t)gc*K + k0 + ac);
      *(h16x8*)&Bs[ar+rr][ac] = val;
    }
    __syncthreads();
    int rsel = lane & 15;
    #pragma unroll
    for (int kk=0; kk<64; kk+=32){
      int ksel = kk + (lane>>4)*8;
      h16x8 af[4], bfr[4];
      #pragma unroll
      for (int i=0;i<4;i++) af[i]  = *(const h16x8*)&As[wr + i*16 + rsel][ksel];
      #pragma unroll
      for (int j=0;j<4;j++) bfr[j] = *(const h16x8*)&Bs[wc + j*16 + rsel][ksel];
      #pragma unroll
      for (int i=0;i<4;i++)
        #pragma unroll
        for (int j=0;j<4;j++)
          acc[i][j] = __builtin_amdgcn_mfma_f32_16x16x32_f16(af[i], bfr[j], acc[i][j], 0, 0, 0);
    }
    __syncthreads();
  }

  float csum[4] = {}, csq[4] = {};
  int colsel = lane & 15, rowsel = (lane>>4)*4;
  #pragma unroll
  for (int j=0;j<4;j++){
    int gc = n0 + wc + j*16 + colsel;
    float bv = (gc < Nc) ? bias[gc] : 0.f;
    #pragma unroll
    for (int i=0;i<4;i++){
      #pragma unroll
      for (int r=0;r<4;r++){
        int gm = m0 + wr + i*16 + rowsel + r;
        if (gm < M && gc < Nc){
          float v = acc[i][j][r] + bv;
          Cout[(size_t)gm*Nc + gc] = (h16)v;
          csum[j] += v; csq[j] += v*v;
        }
      }
    }
  }
  if (stats){
    ((float*)sred)[t] = 0.f;
    __syncthreads();
    #pragma unroll
    for (int j=0;j<4;j++){
      int lc = wc + j*16 + colsel;
      atomicAdd(&sred[0][lc], csum[j]);
      atomicAdd(&sred[1][lc], csq[j]);
    }
    __syncthreads();
    if (t < 128){
      int gc = n0 + t;
      if (gc < Nc){
        atomicAdd(&stats[gc],      sred[0][t]);
        atomicAdd(&stats[Nc + gc], sred[1][t]);
      }
    }
  }
}

// ---------------- BN finalize ----------------
__global__ void k_bnfin(const float* __restrict__ stats, const float* __restrict__ g,
                        const float* __restrict__ be, float invM, int C,
                        float* __restrict__ scale, float* __restrict__ shift){
  int c = blockIdx.x*blockDim.x + threadIdx.x;
  if (c < C){
    float m = stats[c]*invM;
    float var = fmaxf(stats[C+c]*invM - m*m, 0.f);
    float inv = rsqrtf(var + EPSB);
    float sc = g[c]*inv;
    scale[c] = sc;
    shift[c] = fmaf(-sc, m, be[c]);
  }
}

// ---------------- BN apply + ReLU on fp16 pairs (head only) ----------------
__global__ void k_bnapply_h(const h16* __restrict__ X, h16* __restrict__ Y,
                            const float* __restrict__ scale, const float* __restrict__ shift,
                            int totalPairs, int pairMask){
  int i = blockIdx.x*256 + threadIdx.x;
  if (i >= totalPairs) return;
  int c0 = 2*(i & pairMask);
  h16x2 u = *(const h16x2*)(X + 2*(size_t)i);
  float x0 = fmaxf(fmaf((float)u[0], scale[c0],   shift[c0]),   0.f);
  float x1 = fmaxf(fmaf((float)u[1], scale[c0+1], shift[c0+1]), 0.f);
  h16x2 o; o[0] = (h16)x0; o[1] = (h16)x1;
  *(h16x2*)(Y + 2*(size_t)i) = o;
}

// ---------------- layer-4 activation + fused atom-weight dot ----------------
__global__ __launch_bounds__(256)
void k_prep4(const h16* __restrict__ X, const float* __restrict__ scale,
             const float* __restrict__ shift, const float* __restrict__ aw,
             const float* __restrict__ ab, h16* __restrict__ X4,
             float* __restrict__ awout, float* __restrict__ wsig){
  int v = (blockIdx.x*256 + threadIdx.x) >> 6;
  int lane = threadIdx.x & 63;
  if (v >= NN) return;
  int c0 = 2*lane;
  h16x2 u = *(const h16x2*)(X + (size_t)v*128 + c0);
  float x0 = fmaxf(fmaf((float)u[0], scale[c0],   shift[c0]),   0.f);
  float x1 = fmaxf(fmaf((float)u[1], scale[c0+1], shift[c0+1]), 0.f);
  h16x2 o; o[0] = (h16)x0; o[1] = (h16)x1;
  *(h16x2*)(X4 + (size_t)v*128 + c0) = o;
  float s = x0*aw[c0] + x1*aw[c0+1];
  #pragma unroll
  for (int oo=32;oo>0;oo>>=1) s += __shfl_xor(s, oo);
  if (lane == 0){
    float tv = s + ab[0];
    awout[v] = tv;
    wsig[v] = sigmoidf_(tv);
  }
}

__global__ void k_bounds(const int* __restrict__ n2g, int* __restrict__ gs, int* __restrict__ ge){
  int v = blockIdx.x*256 + threadIdx.x;
  if (v < NN){
    int g = n2g[v];
    atomicMin(&gs[g], v);
    atomicMax(&ge[g], v+1);
  }
}

// ---------------- readout: one block (4 waves) per graph ----------------
__global__ __launch_bounds__(256)
void k_readout4(const h16* __restrict__ X4, const float* __restrict__ wsig,
                const int* __restrict__ gs, const int* __restrict__ ge,
                h16* __restrict__ hg){
  __shared__ float red[4][128];
  int g = blockIdx.x;
  int t = threadIdx.x, w = t>>6, lane = t&63;
  int s = gs[g], e = ge[g];
  int c0 = 2*lane;
  float a0=0.f, a1=0.f;
  for (int n = s + w; n < e; n += 4){
    float wn = wsig[n];
    h16x2 u = *(const h16x2*)(X4 + (size_t)n*128 + c0);
    a0 = fmaf((float)u[0], wn, a0);
    a1 = fmaf((float)u[1], wn, a1);
  }
  red[w][c0] = a0; red[w][c0+1] = a1;
  __syncthreads();
  if (w == 0){
    a0 = red[0][c0] + red[1][c0] + red[2][c0] + red[3][c0];
    a1 = red[0][c0+1] + red[1][c0+1] + red[2][c0+1] + red[3][c0+1];
    h16x2 o; o[0] = (h16)a0; o[1] = (h16)a1;
    *(h16x2*)(hg + (size_t)g*128 + c0) = o;
  }
}

// ---------------- final small GEMM + sigmoid ----------------
__global__ void k_final(const h16* __restrict__ y2, const float* __restrict__ Wf2,
                        const float* __restrict__ bf2v, float* __restrict__ out){
  int idx = blockIdx.x*256 + threadIdx.x;
  if (idx >= NG*67) return;
  int g = idx / 67, c = idx % 67;
  float s = bf2v[c];
  const h16* row = y2 + (size_t)g*256;
  for (int k=0;k<256;k+=2){
    h16x2 u = *(const h16x2*)(row + k);
    s = fmaf((float)u[0], Wf2[(size_t)k*67 + c], s);
    s = fmaf((float)u[1], Wf2[(size_t)(k+1)*67 + c], s);
  }
  out[(size_t)g*67 + c] = sigmoidf_(s);
}

extern "C" void kernel_launch(void* const* d_in, const int* in_sizes, int n_in,
                              void* d_out, int out_size, void* d_ws, size_t ws_size,
                              hipStream_t stream){
  const float* h   = (const float*)d_in[0];
  const int*   src = (const int*)d_in[1];
  const int*   dst = (const int*)d_in[2];
  const int*   n2g = (const int*)d_in[3];
  const float* W1  = (const float*)d_in[4];
  const float* b1  = (const float*)d_in[5];
  const float* g1  = (const float*)d_in[6];
  const float* be1 = (const float*)d_in[7];
  const float* W2s = (const float*)d_in[8];
  const float* b2s = (const float*)d_in[9];
  const float* g2s = (const float*)d_in[10];
  const float* be2s= (const float*)d_in[11];
  const float* aw  = (const float*)d_in[12];
  const float* ab  = (const float*)d_in[13];
  const float* Wf1 = (const float*)d_in[14];
  const float* bf1 = (const float*)d_in[15];
  const float* gf1 = (const float*)d_in[16];
  const float* bef1= (const float*)d_in[17];
  const float* Wl  = (const float*)d_in[18];
  const float* bl  = (const float*)d_in[19];
  const float* gl  = (const float*)d_in[20];
  const float* bel = (const float*)d_in[21];
  const float* Wf2 = (const float*)d_in[22];
  const float* bf2v= (const float*)d_in[23];
  float* out = (float*)d_out;

  char* p = (char*)d_ws;
  auto carve = [&](size_t bytes)->void*{
    void* r = (void*)p; p += (bytes + 255) & ~(size_t)255; return r;
  };
  h16* X    = (h16*)carve((size_t)(NN+1)*128*2);   // GEMM out (pre-BN) + dummy row NN
  h16* AGG  = (h16*)carve((size_t)NN*128*2);       // gather out; hn & X4 alias
  h16* A38  = (h16*)carve((size_t)NN*64*2);        // layer-1 GEMM input
  int* eidx = (int*)carve((size_t)(NE + 4*NN)*4);  // aligned-padded CSR
  int* off  = (int*)carve((size_t)(NN+1)*4);
  int* bsum = (int*)carve(512*4);
  int* degO = (int*)carve((size_t)NN*4);
  int* cnt  = (int*)carve((size_t)NN*4);
  int* cnt2 = (int*)carve((size_t)NN*4);
  float* ns = (float*)carve((size_t)(NN+1)*4);
  float* nd = (float*)carve((size_t)NN*4);
  float* wsig = (float*)carve((size_t)NN*4);
  int* gs   = (int*)carve((size_t)NG*4);
  int* ge   = (int*)carve((size_t)NG*4);
  h16* hg   = (h16*)carve((size_t)NG*128*2);
  h16* y1p  = (h16*)carve((size_t)NG*512*2);
  h16* y1   = (h16*)carve((size_t)NG*512*2);
  h16* y2p  = (h16*)carve((size_t)NG*256*2);
  h16* y2   = (h16*)carve((size_t)NG*256*2);
  float* stats = (float*)carve(4096*4);
  float* scale = (float*)carve(512*4);
  float* shift = (float*)carve(512*4);
  h16* W1t  = (h16*)carve((size_t)128*64*2);
  h16* W2t  = (h16*)carve((size_t)3*128*128*2);
  h16* Wf1t = (h16*)carve((size_t)512*128*2);
  h16* Wlt  = (h16*)carve((size_t)256*512*2);

  h16* hn = AGG;            // fp16 [(NN+1)][40] = 8MB ⊂ AGG (dead before AGG written)
  h16* X4 = AGG;            // layer-4 activations (AGG dead after last mgemm)

  float* st1  = stats;
  float* st2a = stats + 256;
  float* st2b = stats + 512;
  float* st2c = stats + 768;
  float* stf1 = stats + 1024;
  float* stl  = stats + 2048;
  float* st2[3] = { st2a, st2b, st2c };

  hipMemsetAsync(degO, 0, (size_t)NN*4, stream);
  hipMemsetAsync(cnt,  0, (size_t)NN*4, stream);
  hipMemsetAsync(cnt2, 0, (size_t)NN*4, stream);
  hipMemsetAsync(stats,0, (size_t)4096*4, stream);
  hipMemsetAsync(gs, 0x7F, (size_t)NG*4, stream);
  hipMemsetAsync(ge, 0,    (size_t)NG*4, stream);
  hipMemsetAsync(X + (size_t)NN*128, 0, 256, stream);   // dummy row

  // weight conversion (independent)
  k_convW<<<(128*64+255)/256, 256, 0, stream>>>(W1, W1t, 38, 128, 64);
  for (int i=0;i<3;i++)
    k_convW<<<(128*128+255)/256, 256, 0, stream>>>(W2s + (size_t)i*128*128, W2t + (size_t)i*128*128, 128, 128, 128);
  k_convW<<<(512*128+255)/256, 256, 0, stream>>>(Wf1, Wf1t, 128, 512, 128);
  k_convW<<<(256*512+255)/256, 256, 0, stream>>>(Wl, Wlt, 512, 256, 512);

  // CSR build
  const int NB = (NN + 255)/256;   // 391
  k_count<<<(NE+255)/256, 256, 0, stream>>>(src, dst, degO, cnt);
  k_norms<<<NB, 256, 0, stream>>>(degO, cnt, ns, nd);
  k_scan1<<<NB, 256, 0, stream>>>(cnt, off, bsum);
  k_scan2<<<1, 512, 0, stream>>>(bsum, off, NB);
  k_scan3<<<NB, 256, 0, stream>>>(off, bsum);
  k_fillcsr<<<(NE+255)/256, 256, 0, stream>>>(src, dst, off, cnt2, eidx);
  k_pad<<<NB, 256, 0, stream>>>(cnt, off, eidx);
  k_bounds<<<NB, 256, 0, stream>>>(n2g, gs, ge);

  const int nodeBlocks = (NN + 3)/4;
  const int gemmBlocks = (NN + 127)/128;

  // layer 1
  k_prep1<<<((NN+1)*40+255)/256, 256, 0, stream>>>(h, ns, hn);
  k_gs40 <<<nodeBlocks, 256, 0, stream>>>(hn, eidx, off, nd, A38);
  k_mgemm<<<dim3(gemmBlocks,1), 256, 0, stream>>>(A38, W1t, b1, X, st1, NN, 64, 128);
  k_bnfin<<<1, 128, 0, stream>>>(st1, g1, be1, 1.0f/(float)NN, 128, scale, shift);

  // layers 2..4 (BN+ReLU+ns fused into gather)
  for (int i=0;i<3;i++){
    k_gs128<<<nodeBlocks, 256, 0, stream>>>(X, eidx, off, ns, nd, scale, shift, AGG);
    k_mgemm<<<dim3(gemmBlocks,1), 256, 0, stream>>>(AGG, W2t + (size_t)i*128*128, b2s + i*128,
                                                    X, st2[i], NN, 128, 128);
    k_bnfin<<<1, 128, 0, stream>>>(st2[i], g2s + i*128, be2s + i*128, 1.0f/(float)NN, 128, scale, shift);
  }

  // layer-4 activation + atom weights
  k_prep4<<<nodeBlocks, 256, 0, stream>>>(X, scale, shift, aw, ab, X4,
                                          out + (size_t)NG*67, wsig);
  k_readout4<<<NG, 256, 0, stream>>>(X4, wsig, gs, ge, hg);

  // head
  k_mgemm<<<dim3(NG/128, 4), 256, 0, stream>>>(hg, Wf1t, bf1, y1p, stf1, NG, 128, 512);
  k_bnfin<<<1, 512, 0, stream>>>(stf1, gf1, bef1, 1.0f/(float)NG, 512, scale, shift);
  k_bnapply_h<<<(NG*256+255)/256, 256, 0, stream>>>(y1p, y1, scale, shift, NG*256, 255);

  k_mgemm<<<dim3(NG/128, 2), 256, 0, stream>>>(y1, Wlt, bl, y2p, stl, NG, 512, 256);
  k_bnfin<<<1, 256, 0, stream>>>(stl, gl, bel, 1.0f/(float)NG, 256, scale, shift);
  k_bnapply_h<<<(NG*128+255)/256, 256, 0, stream>>>(y2p, y2, scale, shift, NG*128, 127);

  k_final<<<(NG*67+255)/256, 256, 0, stream>>>(y2, Wf2, bf2v, out);
}